// Round 7
// baseline (415.837 us; speedup 1.0000x reference)
//
#include <hip/hip_runtime.h>
#include <math.h>

#define BB  16
#define TT  1024
#define NN  128
#define WIN 30
#define NWD 498          // number of windows
#define DM  256          // D_MODEL
#define IND 384          // 3*N

#define INV_W (1.0f/498.0f)

#define SARR (BB*NN*NN)  // one moment-sum array

// workspace offsets in floats
#define OFF_A     0                        // rstd/sqrt(29) per (b,w,ch)
#define OFF_G     (OFF_A    + BB*NWD*NN)   // sqrt(30)*mu*a per (b,w,ch)
#define OFF_S     (OFF_G    + BB*NWD*NN)   // S1..S8, 8 arrays of SARR
#define OFF_CM2   (OFF_S    + 8*SARR)
#define OFF_CM4   (OFF_CM2  + SARR)
#define OFF_CM8   (OFF_CM4  + SARR)
#define OFF_ASUM  (OFF_CM8  + SARR)
#define OFF_ANORM (OFF_ASUM + SARR)
#define OFF_X     (OFF_ANORM + SARR)
#define OFF_BUFA  (OFF_X    + BB*NN*IND)
#define OFF_BUFB  (OFF_BUFA + BB*NN*DM)

// ---------------------------------------------------------------- K1: sliding per-window channel stats
// grid = BB*16 (16 chunks of ~32 windows), block = 128 (one thread per channel)
__global__ __launch_bounds__(128) void k1_stats(const float* __restrict__ x, float* __restrict__ ws) {
    int bx = blockIdx.x;
    int c = bx & 15, b = bx >> 4;
    int w0 = c*32, w1 = min(NWD, w0+32);
    int n = threadIdx.x;
    const float* xp = x + (size_t)b*TT*NN + n;

    float sum = 0.f, sq = 0.f;
    for (int t = 2*w0; t < 2*w0 + WIN; ++t) {
        float v = xp[(size_t)t*NN];
        sum += v; sq = fmaf(v, v, sq);
    }
    for (int w = w0; w < w1; ++w) {
        if (w > w0) {
            float o0 = xp[(size_t)(2*w-2)*NN], o1 = xp[(size_t)(2*w-1)*NN];
            float n0 = xp[(size_t)(2*w+28)*NN], n1 = xp[(size_t)(2*w+29)*NN];
            sum += (n0 + n1) - (o0 + o1);
            sq  += (n0*n0 + n1*n1) - (o0*o0 + o1*o1);
        }
        float mean = sum * (1.0f/30.0f);
        float ss = sq - 30.0f*mean*mean;
        float var = fmaxf(ss * (1.0f/29.0f), 1e-8f);
        float a = (1.0f / sqrtf(var)) * 0.185695338f;   // fold 1/sqrt(29)
        ws[OFF_A + ((size_t)b*NWD + w)*NN + n] = a;
        ws[OFF_G + ((size_t)b*NWD + w)*NN + n] = mean * a * 5.477225575f;   // sqrt(30)*mu*a
    }
}

// ---------------------------------------------------------------- K24: incremental sliding cross-products
// No LDS, no barriers: all operands stream from global (L1/L2-hot; x = 8 MB/batch slice).
// Symmetric: 6 slabs {i<64 x all j, i>=64 x j>=64}. 8 window-chunks of 63.
// XCD swizzle: all 8 chunks of a (b,slab) pair share bx%8 -> same XCD (presumed
// round-robin dispatch) -> S-array atomics resolve in one XCD's L2, no ping-pong.
__global__ __launch_bounds__(256) __attribute__((amdgpu_waves_per_eu(4, 4)))
void k24_inc(const float* __restrict__ x, float* __restrict__ ws) {
    int bx = blockIdx.x;                 // 768 = 8 xcd * 12 pairs * 8 chunks
    int xcd = bx & 7, r = bx >> 3;       // r: 0..95
    int pair = xcd*12 + (r % 12);        // 0..95 = b*6 + slab
    int chunk = r / 12;                  // 0..7
    int b = pair / 6, slab = pair % 6;
    const char IS[6] = {0,0,0,0,1,1};
    const char JS[6] = {0,1,2,3,2,3};
    int is = IS[slab], js = JS[slab];
    int w0 = chunk * 63, w1 = min(NWD, w0 + 63);
    int tid = threadIdx.x;
    int jg = tid & 7, ig = tid >> 3;
    int i0 = is*64 + ig*2;               // 2 rows (even -> 8B aligned)
    int j0 = js*32 + jg*4;               // 4 cols (16B aligned)

    const float* xi_p = x + (size_t)b*TT*NN + i0;
    const float* xj_p = x + (size_t)b*TT*NN + j0;
    const float* Ai = ws + OFF_A + (size_t)b*NWD*NN + i0;
    const float* Aj = ws + OFF_A + (size_t)b*NWD*NN + j0;
    const float* Gi = ws + OFF_G + (size_t)b*NWD*NN + i0;
    const float* Gj = ws + OFF_G + (size_t)b*NWD*NN + j0;

    float P[2][4];
    float S1[2][4], S2[2][4], S3[2][4], S4[2][4], S5[2][4], S6[2][4], S7[2][4], S8[2][4];
#pragma unroll
    for (int p=0;p<2;++p)
#pragma unroll
        for (int q=0;q<4;++q) {
            P[p][q]=0.f;
            S1[p][q]=0.f;S2[p][q]=0.f;S3[p][q]=0.f;S4[p][q]=0.f;
            S5[p][q]=0.f;S6[p][q]=0.f;S7[p][q]=0.f;S8[p][q]=0.f;
        }

    auto moments = [&](int w) {
        float2 ai = *(const float2*)(Ai + (size_t)w*NN);
        float2 gi = *(const float2*)(Gi + (size_t)w*NN);
        float4 aj = *(const float4*)(Aj + (size_t)w*NN);
        float4 gj = *(const float4*)(Gj + (size_t)w*NN);
        float av[2] = {ai.x, ai.y};
        float mg[2] = {-gi.x, -gi.y};
        float aw[4] = {aj.x, aj.y, aj.z, aj.w};
        float gw[4] = {gj.x, gj.y, gj.z, gj.w};
#pragma unroll
        for (int p=0;p<2;++p)
#pragma unroll
            for (int q=0;q<4;++q) {
                float aa  = av[p]*aw[q];
                float ngg = mg[p]*gw[q];
                float c   = fmaf(P[p][q], aa, ngg);
                float c2 = c*c;
                float c3 = c2*c;
                float c4 = c2*c2;
                S1[p][q] += c;
                S2[p][q] += c2;
                S3[p][q] += c3;
                S4[p][q] += c4;
                S5[p][q] = fmaf(c4, c,  S5[p][q]);
                S6[p][q] = fmaf(c3, c3, S6[p][q]);
                S7[p][q] = fmaf(c3, c4, S7[p][q]);
                S8[p][q] = fmaf(c4, c4, S8[p][q]);
            }
    };

    // P init for window w0
#pragma unroll 6
    for (int k = 0; k < WIN; ++k) {
        size_t t = (size_t)(2*w0 + k)*NN;
        float2 xi = *(const float2*)(xi_p + t);
        float4 xj = *(const float4*)(xj_p + t);
        float av[2] = {xi.x, xi.y};
        float bv[4] = {xj.x, xj.y, xj.z, xj.w};
#pragma unroll
        for (int p=0;p<2;++p)
#pragma unroll
            for (int q=0;q<4;++q) P[p][q] = fmaf(av[p], bv[q], P[p][q]);
    }
    moments(w0);

    for (int w = w0 + 1; w < w1; ++w) {
        size_t tA = (size_t)(2*w - 2)*NN,  tB = (size_t)(2*w - 1)*NN;
        size_t tC = (size_t)(2*w + 28)*NN, tD = (size_t)(2*w + 29)*NN;
        float2 xiA = *(const float2*)(xi_p + tA);
        float2 xiB = *(const float2*)(xi_p + tB);
        float2 xiC = *(const float2*)(xi_p + tC);
        float2 xiD = *(const float2*)(xi_p + tD);
        float4 xjA = *(const float4*)(xj_p + tA);
        float4 xjB = *(const float4*)(xj_p + tB);
        float4 xjC = *(const float4*)(xj_p + tC);
        float4 xjD = *(const float4*)(xj_p + tD);
        float avA[2] = {-xiA.x, -xiA.y}, bvA[4] = {xjA.x, xjA.y, xjA.z, xjA.w};
        float avB[2] = {-xiB.x, -xiB.y}, bvB[4] = {xjB.x, xjB.y, xjB.z, xjB.w};
        float avC[2] = { xiC.x,  xiC.y}, bvC[4] = {xjC.x, xjC.y, xjC.z, xjC.w};
        float avD[2] = { xiD.x,  xiD.y}, bvD[4] = {xjD.x, xjD.y, xjD.z, xjD.w};
#pragma unroll
        for (int p=0;p<2;++p)
#pragma unroll
            for (int q=0;q<4;++q) {
                float v = P[p][q];
                v = fmaf(avA[p], bvA[q], v);
                v = fmaf(avB[p], bvB[q], v);
                v = fmaf(avC[p], bvC[q], v);
                v = fmaf(avD[p], bvD[q], v);
                P[p][q] = v;
            }
        moments(w);
    }

    // ---- atomic epilogue (local-XCD L2 resident given the swizzle)
    float* base = ws + OFF_S + (size_t)b*NN*NN;
#pragma unroll
    for (int p=0;p<2;++p)
#pragma unroll
        for (int q=0;q<4;++q) {
            size_t o = (size_t)(i0+p)*NN + (j0+q);
            atomicAdd(base + 0*SARR + o, S1[p][q]);
            atomicAdd(base + 1*SARR + o, S2[p][q]);
            atomicAdd(base + 2*SARR + o, S3[p][q]);
            atomicAdd(base + 3*SARR + o, S4[p][q]);
            atomicAdd(base + 4*SARR + o, S5[p][q]);
            atomicAdd(base + 5*SARR + o, S6[p][q]);
            atomicAdd(base + 6*SARR + o, S7[p][q]);
            atomicAdd(base + 7*SARR + o, S8[p][q]);
        }
}

// ---------------------------------------------------------------- Kcomb: reconstruct centered moments from S1..S8
// S is symmetric; k24 only filled i<64 (all j) and i>=64,j>=64 -> read (lo,hi) ordered entry.
__global__ __launch_bounds__(256) void kcomb(float* __restrict__ ws) {
    int idx = blockIdx.x*256 + threadIdx.x;   // over BB*NN*NN
    int i = (idx >> 7) & 127, j = idx & 127;
    float cm2, cm4, cm8;
    if (i == j) {
        cm2 = 0.f; cm4 = 0.f; cm8 = 0.f;      // corr diag == 1 every window -> centered == 0
    } else {
        int lo = min(i, j), hi = max(i, j);
        int bbase = idx & ~(NN*NN - 1);
        const float* S = ws + OFF_S + bbase + lo*NN + hi;
        float e1 = S[0*SARR]*INV_W, e2 = S[1*SARR]*INV_W, e3 = S[2*SARR]*INV_W, e4 = S[3*SARR]*INV_W;
        float e5 = S[4*SARR]*INV_W, e6 = S[5*SARR]*INV_W, e7 = S[6*SARR]*INV_W, e8 = S[7*SARR]*INV_W;
        float m  = e1;
        float m2 = m*m, m3 = m2*m, m4 = m2*m2, m5 = m4*m, m6 = m3*m3, m8 = m4*m4;
        cm2 = e2 - m2;
        cm4 = e4 - 4.f*m*e3 + 6.f*m2*e2 - 3.f*m4;
        cm8 = e8 - 8.f*m*e7 + 28.f*m2*e6 - 56.f*m3*e5 + 70.f*m4*e4
                 - 56.f*m5*e3 + 28.f*m6*e2 - 7.f*m8;
    }
    ws[OFF_CM2 + idx] = cm2;
    ws[OFF_CM4 + idx] = cm4;
    ws[OFF_CM8 + idx] = cm8;
}

// ---------------------------------------------------------------- K5: rowwise_corr per (b, d, j-half), accumulate A_sum
__global__ __launch_bounds__(256) void k5_rowcorr(float* __restrict__ ws) {
    __shared__ float Xc[NN][NN+1];
    __shared__ float rmn[NN];
    __shared__ float iden[NN];
    int t = blockIdx.x;
    int jh = t & 1; int di = (t >> 1) % 3; int b = t / 6;
    const float* cm = ws + (di==0 ? OFF_CM2 : (di==1 ? OFF_CM4 : OFF_CM8)) + (size_t)b*NN*NN;
    int tid = threadIdx.x;
    for (int idx = tid; idx < NN*NN; idx += 256) {
        int n = idx >> 7, f = idx & 127;
        Xc[n][f] = cm[idx];
    }
    __syncthreads();
    if (tid < NN) {
        float s = 0.f;
        for (int f = 0; f < NN; ++f) s += Xc[tid][f];
        rmn[tid] = s * (1.0f/NN);
    }
    __syncthreads();
    for (int idx = tid; idx < NN*NN; idx += 256) {
        int n = idx >> 7, f = idx & 127;
        Xc[n][f] -= rmn[n];
    }
    __syncthreads();
    if (tid < NN) {
        float s = 0.f;
        for (int f = 0; f < NN; ++f) { float v = Xc[tid][f]; s = fmaf(v, v, s); }
        iden[tid] = 1.0f/sqrtf(fmaxf(s, 1e-8f));
    }
    __syncthreads();
    // output: all 128 rows x 64 cols (jh). 16x16 thread grid, 8x4 per thread.
    int n0 = (tid >> 4)*8, m0 = jh*64 + (tid & 15)*4;
    float acc[8][4];
#pragma unroll
    for (int k=0;k<8;++k)
#pragma unroll
        for (int l=0;l<4;++l) acc[k][l] = 0.f;
    for (int f = 0; f < NN; ++f) {
        float an[8], am[4];
#pragma unroll
        for (int k=0;k<8;++k) an[k] = Xc[n0+k][f];
#pragma unroll
        for (int l=0;l<4;++l) am[l] = Xc[m0+l][f];
#pragma unroll
        for (int k=0;k<8;++k)
#pragma unroll
            for (int l=0;l<4;++l) acc[k][l] = fmaf(an[k], am[l], acc[k][l]);
    }
    float* As = ws + OFF_ASUM + (size_t)b*NN*NN;
#pragma unroll
    for (int k=0;k<8;++k)
#pragma unroll
        for (int l=0;l<4;++l) {
            int gi = n0+k, gj = m0+l;
            float v = acc[k][l]*iden[gi]*iden[gj];
            if (gi == gj) v = 1.0f;
            atomicAdd(&As[gi*NN+gj], v);
        }
}

// ---------------------------------------------------------------- K6: symmetrize + normalize adjacency
__global__ __launch_bounds__(256) void k6_anorm(float* __restrict__ ws) {
    __shared__ float As[NN][NN+1];
    __shared__ float dis[NN];
    int b = blockIdx.x;
    const float* Asum = ws + OFF_ASUM + (size_t)b*NN*NN;
    int tid = threadIdx.x;
    for (int idx = tid; idx < NN*NN; idx += 256) {
        int n = idx >> 7, m = idx & 127;
        As[n][m] = (Asum[n*NN+m] + Asum[m*NN+n]) * (1.0f/6.0f);  // mean-of-3 then 0.5*(A+A^T)
    }
    __syncthreads();
    if (tid < NN) {
        float d = 1.0f;                       // +I diag
        for (int m = 0; m < NN; ++m) d += As[tid][m];
        dis[tid] = sqrtf(1.0f / fmaxf(d, 1e-8f));
    }
    __syncthreads();
    float* An = ws + OFF_ANORM + (size_t)b*NN*NN;
    for (int idx = tid; idx < NN*NN; idx += 256) {
        int n = idx >> 7, m = idx & 127;
        float v = As[n][m] + (n==m ? 1.0f : 0.0f);
        An[idx] = v * dis[n] * dis[m];
    }
}

// ---------------------------------------------------------------- K7: build X (concat cm2,4,8) + layernorm
__global__ __launch_bounds__(128) void k7_ln(const float* __restrict__ gamma, const float* __restrict__ beta,
                                             float* __restrict__ ws) {
    __shared__ float red[128];
    int row = blockIdx.x;   // b*NN + n
    int tid = threadIdx.x;
    float v0 = ws[OFF_CM2 + (size_t)row*NN + tid];
    float v1 = ws[OFF_CM4 + (size_t)row*NN + tid];
    float v2 = ws[OFF_CM8 + (size_t)row*NN + tid];
    red[tid] = v0+v1+v2;
    __syncthreads();
    for (int o = 64; o > 0; o >>= 1) { if (tid < o) red[tid] += red[tid+o]; __syncthreads(); }
    float mean = red[0] * (1.0f/IND);
    __syncthreads();
    float d0 = v0-mean, d1 = v1-mean, d2 = v2-mean;
    red[tid] = d0*d0 + d1*d1 + d2*d2;
    __syncthreads();
    for (int o = 64; o > 0; o >>= 1) { if (tid < o) red[tid] += red[tid+o]; __syncthreads(); }
    float rstd = 1.0f / sqrtf(red[0]*(1.0f/IND) + 1e-5f);
    float* X = ws + OFF_X + (size_t)row*IND;
    X[tid]     = d0*rstd*gamma[tid]     + beta[tid];
    X[tid+128] = d1*rstd*gamma[tid+128] + beta[tid+128];
    X[tid+256] = d2*rstd*gamma[tid+256] + beta[tid+256];
}

// ---------------------------------------------------------------- K8: dense (rows x K) @ (K x 256) + bias
__global__ __launch_bounds__(256) void k8_gemm(const float* __restrict__ Wt, const float* __restrict__ bias,
                                               const float* __restrict__ in, float* __restrict__ out, int K) {
    __shared__ float Xs[8][IND];
    int r0 = blockIdx.x * 8;
    int tid = threadIdx.x;
    for (int r = 0; r < 8; ++r)
        for (int c = tid; c < K; c += 256)
            Xs[r][c] = in[(size_t)(r0+r)*K + c];
    __syncthreads();
    float acc[8];
#pragma unroll
    for (int r = 0; r < 8; ++r) acc[r] = bias[tid];
    for (int k = 0; k < K; ++k) {
        float wv = Wt[(size_t)k*DM + tid];
#pragma unroll
        for (int r = 0; r < 8; ++r) acc[r] = fmaf(Xs[r][k], wv, acc[r]);
    }
#pragma unroll
    for (int r = 0; r < 8; ++r) out[(size_t)(r0+r)*DM + tid] = acc[r];
}

// ---------------------------------------------------------------- K9: H = relu(A_norm @ Z)
__global__ __launch_bounds__(256) void k9_prop(const float* __restrict__ Anorm, const float* __restrict__ Zin,
                                               float* __restrict__ out) {
    __shared__ float Ar[8][NN];
    int bx = blockIdx.x;
    int b = bx >> 4, n0 = (bx & 15)*8;
    int tid = threadIdx.x;
    const float* A = Anorm + (size_t)b*NN*NN;
    if (tid < NN) {
#pragma unroll
        for (int r = 0; r < 8; ++r) Ar[r][tid] = A[(n0+r)*NN + tid];
    }
    __syncthreads();
    float acc[8] = {0,0,0,0,0,0,0,0};
    const float* Z = Zin + (size_t)b*NN*DM;
    for (int m = 0; m < NN; ++m) {
        float z = Z[(size_t)m*DM + tid];
#pragma unroll
        for (int r = 0; r < 8; ++r) acc[r] = fmaf(Ar[r][m], z, acc[r]);
    }
    float* O = out + (size_t)b*NN*DM;
#pragma unroll
    for (int r = 0; r < 8; ++r) O[(size_t)(n0+r)*DM + tid] = fmaxf(acc[r], 0.0f);
}

// ---------------------------------------------------------------- K12: mean-pool + sigmoid head
__global__ __launch_bounds__(256) void k12_head(const float* __restrict__ H, const float* __restrict__ Wc,
                                                const float* __restrict__ bc, float* __restrict__ outp) {
    __shared__ float red[256];
    int b = blockIdx.x, tid = threadIdx.x;
    float s = 0.f;
    for (int n = 0; n < NN; ++n) s += H[((size_t)b*NN+n)*DM + tid];
    red[tid] = s * (1.0f/NN) * Wc[tid];
    __syncthreads();
    for (int o = 128; o > 0; o >>= 1) { if (tid < o) red[tid] += red[tid+o]; __syncthreads(); }
    if (tid == 0) outp[b] = 1.0f/(1.0f + expf(-(red[0] + bc[0])));
}

// ----------------------------------------------------------------
extern "C" void kernel_launch(void* const* d_in, const int* in_sizes, int n_in,
                              void* d_out, int out_size, void* d_ws, size_t ws_size,
                              hipStream_t stream) {
    (void)in_sizes; (void)n_in; (void)out_size; (void)ws_size;
    const float* x     = (const float*)d_in[0];
    const float* gamma = (const float*)d_in[1];
    const float* beta  = (const float*)d_in[2];
    const float* W1    = (const float*)d_in[3];
    const float* b1    = (const float*)d_in[4];
    const float* W2    = (const float*)d_in[5];
    const float* b2    = (const float*)d_in[6];
    const float* Wc    = (const float*)d_in[7];
    const float* bc    = (const float*)d_in[8];
    float* ws  = (float*)d_ws;
    float* out = (float*)d_out;

    // zero the atomic accumulators: S1..S8 and Asum
    hipMemsetAsync(ws + OFF_S,    0, (size_t)(8*SARR)*sizeof(float), stream);
    hipMemsetAsync(ws + OFF_ASUM, 0, (size_t)SARR*sizeof(float), stream);

    k1_stats   <<<BB*16,       128, 0, stream>>>(x, ws);
    k24_inc    <<<BB*6*8,      256, 0, stream>>>(x, ws);
    kcomb      <<<BB*NN*NN/256,256, 0, stream>>>(ws);
    k5_rowcorr <<<BB*3*2,      256, 0, stream>>>(ws);
    k6_anorm   <<<BB,          256, 0, stream>>>(ws);
    k7_ln      <<<BB*NN,       128, 0, stream>>>(gamma, beta, ws);
    k8_gemm    <<<BB*NN/8,     256, 0, stream>>>(W1, b1, ws + OFF_X,    ws + OFF_BUFA, IND);
    k9_prop    <<<BB*16,       256, 0, stream>>>(ws + OFF_ANORM, ws + OFF_BUFA, ws + OFF_BUFB);
    k8_gemm    <<<BB*NN/8,     256, 0, stream>>>(W2, b2, ws + OFF_BUFB, ws + OFF_BUFA, DM);
    k9_prop    <<<BB*16,       256, 0, stream>>>(ws + OFF_ANORM, ws + OFF_BUFA, ws + OFF_BUFB);
    k12_head   <<<BB,          256, 0, stream>>>(ws + OFF_BUFB, Wc, bc, out);
}

// Round 8
// 273.540 us; speedup vs baseline: 1.5202x; 1.5202x over previous
//
#include <hip/hip_runtime.h>
#include <math.h>

#define BB  16
#define TT  1024
#define NN  128
#define WIN 30
#define NWD 498          // number of windows
#define DM  256          // D_MODEL
#define IND 384          // 3*N
#define GW  9            // windows per staging group in k24

#define INV_W (1.0f/498.0f)

#define SARR (BB*NN*NN)  // one b-major NxN array

// workspace offsets in floats
#define OFF_A     0                        // rstd/sqrt(29) per (b,w,ch)
#define OFF_G     (OFF_A    + BB*NWD*NN)   // sqrt(30)*mu*a per (b,w,ch)
#define OFF_CM2   (OFF_G    + BB*NWD*NN)
#define OFF_CM4   (OFF_CM2  + SARR)
#define OFF_CM8   (OFF_CM4  + SARR)
#define OFF_PART  (OFF_CM8  + SARR)        // 768 blocks x 16384 floats = 12.58M floats
// PART is consumed by kred before any of these are written -> alias the tail of ws:
#define OFF_ASUM  OFF_PART
#define OFF_ANORM (OFF_ASUM + SARR)
#define OFF_X     (OFF_ANORM + SARR)
#define OFF_BUFA  (OFF_X    + BB*NN*IND)
#define OFF_BUFB  (OFF_BUFA + BB*NN*DM)

// ---------------------------------------------------------------- K1: sliding per-window channel stats
__global__ __launch_bounds__(128) void k1_stats(const float* __restrict__ x, float* __restrict__ ws) {
    int bx = blockIdx.x;
    int c = bx & 15, b = bx >> 4;
    int w0 = c*32, w1 = min(NWD, w0+32);
    int n = threadIdx.x;
    const float* xp = x + (size_t)b*TT*NN + n;

    float sum = 0.f, sq = 0.f;
    for (int t = 2*w0; t < 2*w0 + WIN; ++t) {
        float v = xp[(size_t)t*NN];
        sum += v; sq = fmaf(v, v, sq);
    }
    for (int w = w0; w < w1; ++w) {
        if (w > w0) {
            float o0 = xp[(size_t)(2*w-2)*NN], o1 = xp[(size_t)(2*w-1)*NN];
            float n0 = xp[(size_t)(2*w+28)*NN], n1 = xp[(size_t)(2*w+29)*NN];
            sum += (n0 + n1) - (o0 + o1);
            sq  += (n0*n0 + n1*n1) - (o0*o0 + o1*o1);
        }
        float mean = sum * (1.0f/30.0f);
        float ss = sq - 30.0f*mean*mean;
        float var = fmaxf(ss * (1.0f/29.0f), 1e-8f);
        float a = (1.0f / sqrtf(var)) * 0.185695338f;   // fold 1/sqrt(29)
        ws[OFF_A + ((size_t)b*NWD + w)*NN + n] = a;
        ws[OFF_G + ((size_t)b*NWD + w)*NN + n] = mean * a * 5.477225575f;   // sqrt(30)*mu*a
    }
}

// ---------------------------------------------------------------- K24: incremental sliding cross-products
// r6 structure (LDS staging, GW-window groups), but NO atomics: each block plain-stores
// its 64 partial floats/thread to a private PART slab; kred reduces the 8 chunks.
// grid = b(16) x slab(6) x chunk(8) = 768; slab = 64 rows x 32 cols (symmetric cover).
__global__ __launch_bounds__(256) __attribute__((amdgpu_waves_per_eu(3, 3)))
void k24_inc(const float* __restrict__ x, float* __restrict__ ws) {
    __shared__ __align__(16) float xr[64][NN];   // circular buffer of x rows, slot = t & 63 (32 KB)
    __shared__ __align__(16) float sa[GW][NN];   // per-window a for the group
    __shared__ __align__(16) float sg[GW][NN];   // per-window g for the group
    int bx = blockIdx.x;
    int wc = bx & 7;                // 8 window chunks of 63
    int slab = (bx >> 3) % 6;
    int b = bx / 48;
    const char IS[6] = {0,0,0,0,1,1};
    const char JS[6] = {0,1,2,3,2,3};
    int is = IS[slab], js = JS[slab];
    int w0 = wc * 63, w1 = min(NWD, w0 + 63);
    int tid = threadIdx.x;
    int jg = tid & 7, ig = tid >> 3;
    int i0 = is*64 + ig*2;          // 2 rows (even -> 8B aligned)
    int j0 = js*32 + jg*4;          // 4 cols (16B aligned)

    const float* xb = x + (size_t)b*TT*NN;
    const float* Ab = ws + OFF_A + (size_t)b*NWD*NN;
    const float* Gb = ws + OFF_G + (size_t)b*NWD*NN;

    float P[2][4];
    float S1[2][4], S2[2][4], S3[2][4], S4[2][4], S5[2][4], S6[2][4], S7[2][4], S8[2][4];
#pragma unroll
    for (int p=0;p<2;++p)
#pragma unroll
        for (int q=0;q<4;++q) {
            P[p][q]=0.f;
            S1[p][q]=0.f;S2[p][q]=0.f;S3[p][q]=0.f;S4[p][q]=0.f;
            S5[p][q]=0.f;S6[p][q]=0.f;S7[p][q]=0.f;S8[p][q]=0.f;
        }

    auto moments = [&](int k) {
        float2 ai = *(const float2*)&sa[k][i0];
        float2 gi = *(const float2*)&sg[k][i0];
        float4 aj = *(const float4*)&sa[k][j0];
        float4 gj = *(const float4*)&sg[k][j0];
        float av[2] = {ai.x, ai.y};
        float mg[2] = {-gi.x, -gi.y};
        float aw[4] = {aj.x, aj.y, aj.z, aj.w};
        float gw[4] = {gj.x, gj.y, gj.z, gj.w};
#pragma unroll
        for (int p=0;p<2;++p)
#pragma unroll
            for (int q=0;q<4;++q) {
                float aa  = av[p]*aw[q];
                float ngg = mg[p]*gw[q];
                float c   = fmaf(P[p][q], aa, ngg);
                float c2 = c*c;
                float c3 = c2*c;
                float c4 = c2*c2;
                S1[p][q] += c;
                S2[p][q] += c2;
                S3[p][q] += c3;
                S4[p][q] += c4;
                S5[p][q] = fmaf(c4, c,  S5[p][q]);
                S6[p][q] = fmaf(c3, c3, S6[p][q]);
                S7[p][q] = fmaf(c3, c4, S7[p][q]);
                S8[p][q] = fmaf(c4, c4, S8[p][q]);
            }
    };

    int rlo = 2*w0;                 // first row not yet staged
    for (int wg = w0; wg < w1; wg += GW) {
        int m = min(GW, w1 - wg);
        __syncthreads();            // prior group's compute done reading xr/sa/sg
        int rhi = 2*(wg + m - 1) + 29;
        int nr = rhi - rlo + 1;
        for (int idx = tid; idx < nr*32; idx += 256) {
            int r = idx >> 5, c4 = idx & 31;
            int t = rlo + r;
            *(float4*)&xr[t & 63][c4*4] = ((const float4*)(xb + (size_t)t*NN))[c4];
        }
        for (int idx = tid; idx < m*32; idx += 256) {
            int k = idx >> 5, c4 = idx & 31;
            *(float4*)&sa[k][c4*4] = ((const float4*)(Ab + (size_t)(wg+k)*NN))[c4];
        }
        for (int idx = tid; idx < m*32; idx += 256) {
            int k = idx >> 5, c4 = idx & 31;
            *(float4*)&sg[k][c4*4] = ((const float4*)(Gb + (size_t)(wg+k)*NN))[c4];
        }
        rlo = rhi + 1;
        __syncthreads();            // staging visible

        int kstart = 0;
        if (wg == w0) {
#pragma unroll 6
            for (int k = 0; k < WIN; ++k) {
                int t = 2*w0 + k;
                float2 xi = *(const float2*)&xr[t & 63][i0];
                float4 xj = *(const float4*)&xr[t & 63][j0];
                float av[2] = {xi.x, xi.y};
                float bv[4] = {xj.x, xj.y, xj.z, xj.w};
#pragma unroll
                for (int p=0;p<2;++p)
#pragma unroll
                    for (int q=0;q<4;++q) P[p][q] = fmaf(av[p], bv[q], P[p][q]);
            }
            moments(0);
            kstart = 1;
        }
        for (int k = kstart; k < m; ++k) {
            int w = wg + k;
            int tr[4] = {2*w - 2, 2*w - 1, 2*w + 28, 2*w + 29};
#pragma unroll
            for (int kk = 0; kk < 4; ++kk) {
                int t = tr[kk];
                float sgn = (kk < 2) ? -1.0f : 1.0f;
                float2 xi = *(const float2*)&xr[t & 63][i0];
                float4 xj = *(const float4*)&xr[t & 63][j0];
                float av[2] = {sgn*xi.x, sgn*xi.y};
                float bv[4] = {xj.x, xj.y, xj.z, xj.w};
#pragma unroll
                for (int p=0;p<2;++p)
#pragma unroll
                    for (int q=0;q<4;++q) P[p][q] = fmaf(av[p], bv[q], P[p][q]);
            }
            moments(k);
        }
    }

    // ---- store epilogue: 64 floats/thread, no atomics
    // layout: PART[bx][arr(8)][tid(256)][elem(8)]; elem e = p*4+q
    float* tp = ws + OFF_PART + (size_t)bx*16384 + tid*8;
#define STORE_ARR(A, S) \
    *(float4*)&tp[(A)*2048]     = make_float4(S[0][0], S[0][1], S[0][2], S[0][3]); \
    *(float4*)&tp[(A)*2048 + 4] = make_float4(S[1][0], S[1][1], S[1][2], S[1][3]);
    STORE_ARR(0, S1) STORE_ARR(1, S2) STORE_ARR(2, S3) STORE_ARR(3, S4)
    STORE_ARR(4, S5) STORE_ARR(5, S6) STORE_ARR(6, S7) STORE_ARR(7, S8)
#undef STORE_ARR
}

// ---------------------------------------------------------------- Kred: reduce 8 chunk-partials -> centered moments
// grid = 96 (b*6+slab), block = 256 (same thread->element mapping as k24).
__global__ __launch_bounds__(256) void kred(float* __restrict__ ws) {
    int pair = blockIdx.x;          // b*6 + slab
    int b = pair / 6, slab = pair % 6;
    const char IS[6] = {0,0,0,0,1,1};
    const char JS[6] = {0,1,2,3,2,3};
    int is = IS[slab], js = JS[slab];
    int tid = threadIdx.x;
    int jg = tid & 7, ig = tid >> 3;

    float E[8][8];
#pragma unroll
    for (int a=0;a<8;++a)
#pragma unroll
        for (int e=0;e<8;++e) E[a][e] = 0.f;

    for (int c = 0; c < 8; ++c) {
        int bx = (b*6 + slab)*8 + c;        // k24's linear block id: b/48, slab, wc=bx&7
        // note: k24's bx decode was wc=bx&7, slab=(bx>>3)%6, b=bx/48 -> bx = b*48 + slab*8 + wc
        const float* tp = ws + OFF_PART + (size_t)(b*48 + slab*8 + c)*16384 + tid*8;
        (void)bx;
#pragma unroll
        for (int a=0;a<8;++a) {
            float4 u = *(const float4*)&tp[a*2048];
            float4 v = *(const float4*)&tp[a*2048 + 4];
            E[a][0]+=u.x; E[a][1]+=u.y; E[a][2]+=u.z; E[a][3]+=u.w;
            E[a][4]+=v.x; E[a][5]+=v.y; E[a][6]+=v.z; E[a][7]+=v.w;
        }
    }

    float* C2 = ws + OFF_CM2 + (size_t)b*NN*NN;
    float* C4 = ws + OFF_CM4 + (size_t)b*NN*NN;
    float* C8 = ws + OFF_CM8 + (size_t)b*NN*NN;
#pragma unroll
    for (int p=0;p<2;++p)
#pragma unroll
        for (int q=0;q<4;++q) {
            int e = p*4 + q;
            int i = is*64 + ig*2 + p;
            int j = js*32 + jg*4 + q;
            float cm2, cm4, cm8;
            if (i == j) {
                cm2 = 0.f; cm4 = 0.f; cm8 = 0.f;
            } else {
                float e1 = E[0][e]*INV_W, e2 = E[1][e]*INV_W, e3 = E[2][e]*INV_W, e4 = E[3][e]*INV_W;
                float e5 = E[4][e]*INV_W, e6 = E[5][e]*INV_W, e7 = E[6][e]*INV_W, e8 = E[7][e]*INV_W;
                float m  = e1;
                float m2 = m*m, m3 = m2*m, m4 = m2*m2, m5 = m4*m, m6 = m3*m3, m8 = m4*m4;
                cm2 = e2 - m2;
                cm4 = e4 - 4.f*m*e3 + 6.f*m2*e2 - 3.f*m4;
                cm8 = e8 - 8.f*m*e7 + 28.f*m2*e6 - 56.f*m3*e5 + 70.f*m4*e4
                         - 56.f*m5*e3 + 28.f*m6*e2 - 7.f*m8;
            }
            C2[i*NN + j] = cm2; C2[j*NN + i] = cm2;
            C4[i*NN + j] = cm4; C4[j*NN + i] = cm4;
            C8[i*NN + j] = cm8; C8[j*NN + i] = cm8;
        }
}

// ---------------------------------------------------------------- K5: rowwise_corr per (b, d, j-half), accumulate A_sum
__global__ __launch_bounds__(256) void k5_rowcorr(float* __restrict__ ws) {
    __shared__ float Xc[NN][NN+1];
    __shared__ float rmn[NN];
    __shared__ float iden[NN];
    int t = blockIdx.x;
    int jh = t & 1; int di = (t >> 1) % 3; int b = t / 6;
    const float* cm = ws + (di==0 ? OFF_CM2 : (di==1 ? OFF_CM4 : OFF_CM8)) + (size_t)b*NN*NN;
    int tid = threadIdx.x;
    for (int idx = tid; idx < NN*NN; idx += 256) {
        int n = idx >> 7, f = idx & 127;
        Xc[n][f] = cm[idx];
    }
    __syncthreads();
    if (tid < NN) {
        float s = 0.f;
        for (int f = 0; f < NN; ++f) s += Xc[tid][f];
        rmn[tid] = s * (1.0f/NN);
    }
    __syncthreads();
    for (int idx = tid; idx < NN*NN; idx += 256) {
        int n = idx >> 7, f = idx & 127;
        Xc[n][f] -= rmn[n];
    }
    __syncthreads();
    if (tid < NN) {
        float s = 0.f;
        for (int f = 0; f < NN; ++f) { float v = Xc[tid][f]; s = fmaf(v, v, s); }
        iden[tid] = 1.0f/sqrtf(fmaxf(s, 1e-8f));
    }
    __syncthreads();
    int n0 = (tid >> 4)*8, m0 = jh*64 + (tid & 15)*4;
    float acc[8][4];
#pragma unroll
    for (int k=0;k<8;++k)
#pragma unroll
        for (int l=0;l<4;++l) acc[k][l] = 0.f;
    for (int f = 0; f < NN; ++f) {
        float an[8], am[4];
#pragma unroll
        for (int k=0;k<8;++k) an[k] = Xc[n0+k][f];
#pragma unroll
        for (int l=0;l<4;++l) am[l] = Xc[m0+l][f];
#pragma unroll
        for (int k=0;k<8;++k)
#pragma unroll
            for (int l=0;l<4;++l) acc[k][l] = fmaf(an[k], am[l], acc[k][l]);
    }
    float* As = ws + OFF_ASUM + (size_t)b*NN*NN;
#pragma unroll
    for (int k=0;k<8;++k)
#pragma unroll
        for (int l=0;l<4;++l) {
            int gi = n0+k, gj = m0+l;
            float v = acc[k][l]*iden[gi]*iden[gj];
            if (gi == gj) v = 1.0f;
            atomicAdd(&As[gi*NN+gj], v);
        }
}

// ---------------------------------------------------------------- K6: symmetrize + normalize adjacency
__global__ __launch_bounds__(256) void k6_anorm(float* __restrict__ ws) {
    __shared__ float As[NN][NN+1];
    __shared__ float dis[NN];
    int b = blockIdx.x;
    const float* Asum = ws + OFF_ASUM + (size_t)b*NN*NN;
    int tid = threadIdx.x;
    for (int idx = tid; idx < NN*NN; idx += 256) {
        int n = idx >> 7, m = idx & 127;
        As[n][m] = (Asum[n*NN+m] + Asum[m*NN+n]) * (1.0f/6.0f);
    }
    __syncthreads();
    if (tid < NN) {
        float d = 1.0f;
        for (int m = 0; m < NN; ++m) d += As[tid][m];
        dis[tid] = sqrtf(1.0f / fmaxf(d, 1e-8f));
    }
    __syncthreads();
    float* An = ws + OFF_ANORM + (size_t)b*NN*NN;
    for (int idx = tid; idx < NN*NN; idx += 256) {
        int n = idx >> 7, m = idx & 127;
        float v = As[n][m] + (n==m ? 1.0f : 0.0f);
        An[idx] = v * dis[n] * dis[m];
    }
}

// ---------------------------------------------------------------- K7: build X (concat cm2,4,8) + layernorm
__global__ __launch_bounds__(128) void k7_ln(const float* __restrict__ gamma, const float* __restrict__ beta,
                                             float* __restrict__ ws) {
    __shared__ float red[128];
    int row = blockIdx.x;   // b*NN + n
    int tid = threadIdx.x;
    float v0 = ws[OFF_CM2 + (size_t)row*NN + tid];
    float v1 = ws[OFF_CM4 + (size_t)row*NN + tid];
    float v2 = ws[OFF_CM8 + (size_t)row*NN + tid];
    red[tid] = v0+v1+v2;
    __syncthreads();
    for (int o = 64; o > 0; o >>= 1) { if (tid < o) red[tid] += red[tid+o]; __syncthreads(); }
    float mean = red[0] * (1.0f/IND);
    __syncthreads();
    float d0 = v0-mean, d1 = v1-mean, d2 = v2-mean;
    red[tid] = d0*d0 + d1*d1 + d2*d2;
    __syncthreads();
    for (int o = 64; o > 0; o >>= 1) { if (tid < o) red[tid] += red[tid+o]; __syncthreads(); }
    float rstd = 1.0f / sqrtf(red[0]*(1.0f/IND) + 1e-5f);
    float* X = ws + OFF_X + (size_t)row*IND;
    X[tid]     = d0*rstd*gamma[tid]     + beta[tid];
    X[tid+128] = d1*rstd*gamma[tid+128] + beta[tid+128];
    X[tid+256] = d2*rstd*gamma[tid+256] + beta[tid+256];
}

// ---------------------------------------------------------------- K8: dense (rows x K) @ (K x 256) + bias
__global__ __launch_bounds__(256) void k8_gemm(const float* __restrict__ Wt, const float* __restrict__ bias,
                                               const float* __restrict__ in, float* __restrict__ out, int K) {
    __shared__ float Xs[8][IND];
    int r0 = blockIdx.x * 8;
    int tid = threadIdx.x;
    for (int r = 0; r < 8; ++r)
        for (int c = tid; c < K; c += 256)
            Xs[r][c] = in[(size_t)(r0+r)*K + c];
    __syncthreads();
    float acc[8];
#pragma unroll
    for (int r = 0; r < 8; ++r) acc[r] = bias[tid];
    for (int k = 0; k < K; ++k) {
        float wv = Wt[(size_t)k*DM + tid];
#pragma unroll
        for (int r = 0; r < 8; ++r) acc[r] = fmaf(Xs[r][k], wv, acc[r]);
    }
#pragma unroll
    for (int r = 0; r < 8; ++r) out[(size_t)(r0+r)*DM + tid] = acc[r];
}

// ---------------------------------------------------------------- K9: H = relu(A_norm @ Z)
__global__ __launch_bounds__(256) void k9_prop(const float* __restrict__ Anorm, const float* __restrict__ Zin,
                                               float* __restrict__ out) {
    __shared__ float Ar[8][NN];
    int bx = blockIdx.x;
    int b = bx >> 4, n0 = (bx & 15)*8;
    int tid = threadIdx.x;
    const float* A = Anorm + (size_t)b*NN*NN;
    if (tid < NN) {
#pragma unroll
        for (int r = 0; r < 8; ++r) Ar[r][tid] = A[(n0+r)*NN + tid];
    }
    __syncthreads();
    float acc[8] = {0,0,0,0,0,0,0,0};
    const float* Z = Zin + (size_t)b*NN*DM;
    for (int m = 0; m < NN; ++m) {
        float z = Z[(size_t)m*DM + tid];
#pragma unroll
        for (int r = 0; r < 8; ++r) acc[r] = fmaf(Ar[r][m], z, acc[r]);
    }
    float* O = out + (size_t)b*NN*DM;
#pragma unroll
    for (int r = 0; r < 8; ++r) O[(size_t)(n0+r)*DM + tid] = fmaxf(acc[r], 0.0f);
}

// ---------------------------------------------------------------- K12: mean-pool + sigmoid head
__global__ __launch_bounds__(256) void k12_head(const float* __restrict__ H, const float* __restrict__ Wc,
                                                const float* __restrict__ bc, float* __restrict__ outp) {
    __shared__ float red[256];
    int b = blockIdx.x, tid = threadIdx.x;
    float s = 0.f;
    for (int n = 0; n < NN; ++n) s += H[((size_t)b*NN+n)*DM + tid];
    red[tid] = s * (1.0f/NN) * Wc[tid];
    __syncthreads();
    for (int o = 128; o > 0; o >>= 1) { if (tid < o) red[tid] += red[tid+o]; __syncthreads(); }
    if (tid == 0) outp[b] = 1.0f/(1.0f + expf(-(red[0] + bc[0])));
}

// ----------------------------------------------------------------
extern "C" void kernel_launch(void* const* d_in, const int* in_sizes, int n_in,
                              void* d_out, int out_size, void* d_ws, size_t ws_size,
                              hipStream_t stream) {
    (void)in_sizes; (void)n_in; (void)out_size; (void)ws_size;
    const float* x     = (const float*)d_in[0];
    const float* gamma = (const float*)d_in[1];
    const float* beta  = (const float*)d_in[2];
    const float* W1    = (const float*)d_in[3];
    const float* b1    = (const float*)d_in[4];
    const float* W2    = (const float*)d_in[5];
    const float* b2    = (const float*)d_in[6];
    const float* Wc    = (const float*)d_in[7];
    const float* bc    = (const float*)d_in[8];
    float* ws  = (float*)d_ws;
    float* out = (float*)d_out;

    k1_stats   <<<BB*16,   128, 0, stream>>>(x, ws);
    k24_inc    <<<BB*6*8,  256, 0, stream>>>(x, ws);
    kred       <<<BB*6,    256, 0, stream>>>(ws);
    // ASUM aliases PART; zero it only after kred has consumed the partials
    hipMemsetAsync(ws + OFF_ASUM, 0, (size_t)SARR*sizeof(float), stream);
    k5_rowcorr <<<BB*3*2,  256, 0, stream>>>(ws);
    k6_anorm   <<<BB,      256, 0, stream>>>(ws);
    k7_ln      <<<BB*NN,   128, 0, stream>>>(gamma, beta, ws);
    k8_gemm    <<<BB*NN/8, 256, 0, stream>>>(W1, b1, ws + OFF_X,    ws + OFF_BUFA, IND);
    k9_prop    <<<BB*16,   256, 0, stream>>>(ws + OFF_ANORM, ws + OFF_BUFA, ws + OFF_BUFB);
    k8_gemm    <<<BB*NN/8, 256, 0, stream>>>(W2, b2, ws + OFF_BUFB, ws + OFF_BUFA, DM);
    k9_prop    <<<BB*16,   256, 0, stream>>>(ws + OFF_ANORM, ws + OFF_BUFA, ws + OFF_BUFB);
    k12_head   <<<BB,      256, 0, stream>>>(ws + OFF_BUFB, Wc, bc, out);
}